// Round 2
// baseline (1140.989 us; speedup 1.0000x reference)
//
#include <hip/hip_runtime.h>
#include <hip/hip_bf16.h>

#define BEV 180
#define NPOS (BEV * BEV)   // 32400
#define MTOT (2 * NPOS)    // 64800
#define IH 64
#define IW 176
#define CIMG 256

typedef __attribute__((ext_vector_type(8))) short bf16x8;
typedef __attribute__((ext_vector_type(4))) float f32x4;

__device__ __forceinline__ void gload_lds16(const void* g, void* l) {
  __builtin_amdgcn_global_load_lds(
      (const __attribute__((address_space(1))) void*)g,
      (__attribute__((address_space(3))) void*)l, 16, 0, 0);
}

// ---------------- zero page ----------------
__global__ void k_zero(unsigned long long* p) { p[threadIdx.x] = 0ULL; }

// ---------------- generic fp32 [B][R][CL] -> [B][CL][R] transpose ----------------
template <typename OT>
__device__ __forceinline__ OT conv_out(float v);
template <>
__device__ __forceinline__ float conv_out<float>(float v) { return v; }
template <>
__device__ __forceinline__ __hip_bfloat16 conv_out<__hip_bfloat16>(float v) { return __float2bfloat16(v); }

template <typename OT>
__global__ void k_transpose(const float* __restrict__ in, OT* __restrict__ out, int R, int CL) {
  __shared__ float tile[32][33];
  const float* inb = in + (size_t)blockIdx.z * R * CL;
  OT* outb = out + (size_t)blockIdx.z * R * CL;
  int c0 = blockIdx.x * 32, r0 = blockIdx.y * 32;
  int tx = threadIdx.x, ty = threadIdx.y;
#pragma unroll
  for (int i = 0; i < 32; i += 8) {
    int r = r0 + ty + i, c = c0 + tx;
    tile[ty + i][tx] = (r < R && c < CL) ? inb[(size_t)r * CL + c] : 0.f;
  }
  __syncthreads();
#pragma unroll
  for (int i = 0; i < 32; i += 8) {
    int c = c0 + ty + i, r = r0 + tx;
    if (c < CL && r < R) outb[(size_t)c * R + r] = conv_out<OT>(tile[tx][ty + i]);
  }
}

// ---------------- projection + bilinear sample -> image_bev NHWC bf16 ----------------
__global__ void k_sample(const float* __restrict__ imgT, const float* __restrict__ l2i,
                         __hip_bfloat16* __restrict__ out) {
  int blk = blockIdx.x;
  int b = blk / NPOS, rem = blk - b * NPOS;
  int hy = rem / BEV, wx = rem - hy * BEV;
  int c = threadIdx.x;
  float gx = -54.f + 0.3f + 0.6f * (float)wx;
  float gy = -54.f + 0.3f + 0.6f * (float)hy;
  const float* L = l2i + b * 12;
  const float* img = imgT + (size_t)b * (IH * IW * CIMG);
  float acc = 0.f, vcnt = 0.f;
#pragma unroll
  for (int zi = 0; zi < 3; ++zi) {
    float z = (float)(zi - 1);
    float p0 = L[0] * gx + L[1] * gy + L[2] * z + L[3];
    float p1 = L[4] * gx + L[5] * gy + L[6] * z + L[7];
    float p2 = L[8] * gx + L[9] * gy + L[10] * z + L[11];
    float d = fmaxf(p2, 1e-5f);
    float px = p0 / d, py = p1 / d;
    if (px >= 0.f && px < 704.f && py >= 0.f && py < 256.f && p2 > 1e-5f) {
      vcnt += 1.f;
      float ix = px * 0.25f - 0.5f, iy = py * 0.25f - 0.5f;
      float xf = floorf(ix), yf = floorf(iy);
      float wx1 = ix - xf, wy1 = iy - yf;
      float wx0 = 1.f - wx1, wy0 = 1.f - wy1;
      int x0 = (int)xf, y0 = (int)yf;
      int x1 = x0 + 1, y1 = y0 + 1;
      bool bx0 = (unsigned)x0 < IW, bx1 = (unsigned)x1 < IW;
      bool by0 = (unsigned)y0 < IH, by1 = (unsigned)y1 < IH;
      float s = 0.f;
      if (bx0 && by0) s += wx0 * wy0 * img[((size_t)y0 * IW + x0) * CIMG + c];
      if (bx1 && by0) s += wx1 * wy0 * img[((size_t)y0 * IW + x1) * CIMG + c];
      if (bx0 && by1) s += wx0 * wy1 * img[((size_t)y1 * IW + x0) * CIMG + c];
      if (bx1 && by1) s += wx1 * wy1 * img[((size_t)y1 * IW + x1) * CIMG + c];
      acc += s;
    }
  }
  out[(size_t)blk * CIMG + c] = __float2bfloat16(acc / fmaxf(vcnt, 1.f));
}

// ---------------- weight pack: w[co][ci][tap] fp32 -> wp[tap][co][ci] bf16 ----------------
__global__ void k_packw(const float* __restrict__ w, __hip_bfloat16* __restrict__ wp,
                        int Co, int Ci, int T) {
  size_t idx = (size_t)blockIdx.x * 256 + threadIdx.x;
  size_t tot = (size_t)Co * Ci * T;
  if (idx >= tot) return;
  int ci = (int)(idx % Ci);
  size_t r = idx / Ci;
  int co = (int)(r % Co);
  int tap = (int)(r / Co);
  wp[idx] = __float2bfloat16(w[((size_t)co * Ci + ci) * T + tap]);
}

// ---------------- BN fold: [4][C] -> [2][C] (scale, bias) ----------------
__global__ void k_packbn(const float* __restrict__ bn, float* __restrict__ sb, int C) {
  int i = blockIdx.x * blockDim.x + threadIdx.x;
  if (i >= C) return;
  float g = bn[i], b = bn[C + i], m = bn[2 * C + i], v = bn[3 * C + i];
  float s = g / sqrtf(v + 1e-5f);
  sb[i] = s;
  sb[C + i] = b - m * s;
}

// ---------------- implicit-GEMM conv: NHWC bf16 in, fused BN+ReLU ----------------
// out[p][co] = relu(BN( sum_{seg,tap,ci} x_seg[b, y+dy, x+dx, ci] * wp[tap][co][segoff+ci] ))
__global__ __launch_bounds__(256) void k_conv(
    const __hip_bfloat16* __restrict__ x0, const __hip_bfloat16* __restrict__ x1,
    int cin0, int cin1,
    const __hip_bfloat16* __restrict__ wp, const float* __restrict__ sb,
    int Cout, int taps, int isFinal,
    __hip_bfloat16* __restrict__ obf, float* __restrict__ of32,
    const __hip_bfloat16* __restrict__ zp) {
  __shared__ __hip_bfloat16 As[128 * 32];
  __shared__ __hip_bfloat16 Bs[128 * 32];
  const int t = threadIdx.x;
  const int w = t >> 6, l = t & 63;
  const int m0 = blockIdx.x * 128, n0 = blockIdx.y * 128;
  const int cinTot = cin0 + cin1;

  int pb[2], pyv[2], pxv[2];
  bool pvalid[2];
#pragma unroll
  for (int i = 0; i < 2; ++i) {
    int row = (w * 2 + i) * 16 + (l >> 2);
    int p = m0 + row;
    pvalid[i] = (p < MTOT);
    int b = p / NPOS;
    int r2 = p - b * NPOS;
    pb[i] = b;
    pyv[i] = r2 / BEV;
    pxv[i] = r2 - (r2 / BEV) * BEV;
  }
  const int lk = (l & 3) * 8;

  f32x4 acc[4][4];
#pragma unroll
  for (int mi = 0; mi < 4; ++mi)
#pragma unroll
    for (int ni = 0; ni < 4; ++ni) acc[mi][ni] = f32x4{0.f, 0.f, 0.f, 0.f};

  const int wm = (w >> 1) * 64, wn = (w & 1) * 64;
  const int ko = (l >> 4) * 8;
  const int ar = wm + (l & 15);
  const int bc = wn + (l & 15);

  for (int seg = 0; seg < 2; ++seg) {
    const __hip_bfloat16* xs = seg ? x1 : x0;
    const int cin = seg ? cin1 : cin0;
    if (cin == 0) continue;
    const int segoff = seg ? cin0 : 0;
    for (int tap = 0; tap < taps; ++tap) {
      const int dy = (taps == 9) ? (tap / 3 - 1) : 0;
      const int dx = (taps == 9) ? (tap - (tap / 3) * 3 - 1) : 0;
      const __hip_bfloat16* asrc[2];
      const __hip_bfloat16* bsrc[2];
#pragma unroll
      for (int i = 0; i < 2; ++i) {
        int yy = pyv[i] + dy, xx = pxv[i] + dx;
        bool ok = pvalid[i] && ((unsigned)yy < BEV) && ((unsigned)xx < BEV);
        asrc[i] = ok ? (xs + (size_t)(pb[i] * NPOS + yy * BEV + xx) * cin + lk) : zp;
        int row = (w * 2 + i) * 16 + (l >> 2);
        bsrc[i] = wp + ((size_t)tap * Cout + n0 + row) * cinTot + segoff + lk;
      }
      const int nkc = cin >> 5;
      for (int kc = 0; kc < nkc; ++kc) {
        __syncthreads();
#pragma unroll
        for (int i = 0; i < 2; ++i) {
          gload_lds16(asrc[i] + kc * 32, &As[(w * 2 + i) * 512]);
          gload_lds16(bsrc[i] + kc * 32, &Bs[(w * 2 + i) * 512]);
        }
        asm volatile("s_waitcnt vmcnt(0)" ::: "memory");
        __syncthreads();
        bf16x8 af[4], bfr[4];
#pragma unroll
        for (int mi = 0; mi < 4; ++mi)
          af[mi] = *(const bf16x8*)&As[(ar + mi * 16) * 32 + ko];
#pragma unroll
        for (int ni = 0; ni < 4; ++ni)
          bfr[ni] = *(const bf16x8*)&Bs[(bc + ni * 16) * 32 + ko];
#pragma unroll
        for (int mi = 0; mi < 4; ++mi)
#pragma unroll
          for (int ni = 0; ni < 4; ++ni)
            acc[mi][ni] = __builtin_amdgcn_mfma_f32_16x16x32_bf16(af[mi], bfr[ni], acc[mi][ni], 0, 0, 0);
      }
    }
  }

  // epilogue: BN + ReLU, store
  float sc[4], bi[4];
#pragma unroll
  for (int ni = 0; ni < 4; ++ni) {
    int cc = n0 + wn + ni * 16 + (l & 15);
    sc[ni] = sb[cc];
    bi[ni] = sb[Cout + cc];
  }
#pragma unroll
  for (int mi = 0; mi < 4; ++mi) {
    int rbase = m0 + wm + mi * 16 + (l >> 4) * 4;
#pragma unroll
    for (int j = 0; j < 4; ++j) {
      int p = rbase + j;
      if (p >= MTOT) continue;
#pragma unroll
      for (int ni = 0; ni < 4; ++ni) {
        int cc = n0 + wn + ni * 16 + (l & 15);
        float v = fmaxf(acc[mi][ni][j] * sc[ni] + bi[ni], 0.f);
        if (isFinal) {
          int b = p / NPOS;
          int r2 = p - b * NPOS;
          of32[((size_t)(b * Cout + cc)) * NPOS + r2] = v;
        } else {
          obf[(size_t)p * Cout + cc] = __float2bfloat16(v);
        }
      }
    }
  }
}

extern "C" void kernel_launch(void* const* d_in, const int* in_sizes, int n_in,
                              void* d_out, int out_size, void* d_ws, size_t ws_size,
                              hipStream_t stream) {
  const float* radar = (const float*)d_in[0];
  const float* imgf = (const float*)d_in[1];
  const float* l2i = (const float*)d_in[2];
  const float* w1 = (const float*)d_in[3];
  const float* bn1 = (const float*)d_in[4];
  const float* w2 = (const float*)d_in[5];
  const float* bn2 = (const float*)d_in[6];
  const float* wf1 = (const float*)d_in[7];
  const float* bnf1 = (const float*)d_in[8];
  const float* wf2 = (const float*)d_in[9];
  const float* bnf2 = (const float*)d_in[10];

  char* ws = (char*)d_ws;
  size_t off = 0;
  auto alloc = [&](size_t bytes) {
    char* p = ws + off;
    off += (bytes + 255) & ~(size_t)255;
    return p;
  };
  char* zp = alloc(4096);
  char* imgT = alloc((size_t)2 * IH * IW * CIMG * 4);   // 23.0 MB fp32 NHWC
  char* ibev = alloc((size_t)MTOT * CIMG * 2);          // 33.2 MB bf16 NHWC
  char* radarT = imgT;                                  // alias: used after imgT/ibev dead
  char* h1 = alloc((size_t)MTOT * 384 * 2);             // 49.8 MB
  char* h2 = alloc((size_t)MTOT * 384 * 2);             // 49.8 MB
  char* f1 = h1;                                        // alias: h1 dead after conv2
  char* wp1 = alloc((size_t)1 * 384 * 256 * 2);
  char* wp2 = alloc((size_t)9 * 384 * 384 * 2);
  char* wpf1 = alloc((size_t)9 * 384 * 768 * 2);
  char* wpf2 = alloc((size_t)9 * 384 * 384 * 2);
  char* sb1 = alloc(2 * 384 * 4);
  char* sb2 = alloc(2 * 384 * 4);
  char* sbf1 = alloc(2 * 384 * 4);
  char* sbf2 = alloc(2 * 384 * 4);

  k_zero<<<1, 512, 0, stream>>>((unsigned long long*)zp);

  dim3 tb(32, 8);
  // img_feat NCHW -> NHWC fp32 (R=256 channels, CL=64*176)
  k_transpose<float><<<dim3((IH * IW + 31) / 32, (CIMG + 31) / 32, 2), tb, 0, stream>>>(
      imgf, (float*)imgT, CIMG, IH * IW);

  // weight + BN packing
  auto packw = [&](const float* src, char* dst, int Co, int Ci, int T) {
    size_t tot = (size_t)Co * Ci * T;
    k_packw<<<(unsigned)((tot + 255) / 256), 256, 0, stream>>>(src, (__hip_bfloat16*)dst, Co, Ci, T);
  };
  packw(w1, wp1, 384, 256, 1);
  packw(w2, wp2, 384, 384, 9);
  packw(wf1, wpf1, 384, 768, 9);
  packw(wf2, wpf2, 384, 384, 9);
  k_packbn<<<2, 256, 0, stream>>>(bn1, (float*)sb1, 384);
  k_packbn<<<2, 256, 0, stream>>>(bn2, (float*)sb2, 384);
  k_packbn<<<2, 256, 0, stream>>>(bnf1, (float*)sbf1, 384);
  k_packbn<<<2, 256, 0, stream>>>(bnf2, (float*)sbf2, 384);

  // sampling -> image_bev NHWC bf16
  k_sample<<<MTOT, 256, 0, stream>>>((const float*)imgT, l2i, (__hip_bfloat16*)ibev);

  dim3 cg(507, 3);
  // conv1: 1x1, image_bev(256) -> h1(384)
  k_conv<<<cg, 256, 0, stream>>>((const __hip_bfloat16*)ibev, nullptr, 256, 0,
                                 (const __hip_bfloat16*)wp1, (const float*)sb1, 384, 1, 0,
                                 (__hip_bfloat16*)h1, nullptr, (const __hip_bfloat16*)zp);
  // radar NCHW -> NHWC bf16 (after conv1: aliases imgT/ibev)
  k_transpose<__hip_bfloat16><<<dim3((NPOS + 31) / 32, (384 + 31) / 32, 2), tb, 0, stream>>>(
      radar, (__hip_bfloat16*)radarT, 384, NPOS);
  // conv2: 3x3, h1(384) -> h2(384)
  k_conv<<<cg, 256, 0, stream>>>((const __hip_bfloat16*)h1, nullptr, 384, 0,
                                 (const __hip_bfloat16*)wp2, (const float*)sb2, 384, 9, 0,
                                 (__hip_bfloat16*)h2, nullptr, (const __hip_bfloat16*)zp);
  // convf1: 3x3, concat(radar, h2)(768) -> f1(384)
  k_conv<<<cg, 256, 0, stream>>>((const __hip_bfloat16*)radarT, (const __hip_bfloat16*)h2, 384, 384,
                                 (const __hip_bfloat16*)wpf1, (const float*)sbf1, 384, 9, 0,
                                 (__hip_bfloat16*)f1, nullptr, (const __hip_bfloat16*)zp);
  // convf2: 3x3, f1(384) -> d_out fp32 NCHW
  k_conv<<<cg, 256, 0, stream>>>((const __hip_bfloat16*)f1, nullptr, 384, 0,
                                 (const __hip_bfloat16*)wpf2, (const float*)sbf2, 384, 9, 1,
                                 nullptr, (float*)d_out, (const __hip_bfloat16*)zp);
}